// Round 6
// baseline (74.372 us; speedup 1.0000x reference)
//
#include <hip/hip_runtime.h>
#include <hip/hip_fp16.h>
#include <string.h>

// Problem constants (match setup_inputs: B=2, N=768, H=W=160)
#define BATCH   2
#define NG      768
#define H_      160
#define W_      160
#define NPIX    (H_ * W_)          // 25600
#define NWAVE   8
#define CHUNK   (NG / NWAVE)       // 96
#define TILE    8
#define TPD     (W_ / TILE)        // 20 tiles per dim
#define NTILE   (TPD * TPD)        // 400
#define EPS2D_  0.3f
#define SZ2_    1.0e-6f            // 0.001^2
#define ALPHA_MAX_ 0.999f
#define KEXP    (-0.7213475204444817f)   // -0.5 * log2(e)
#define LN_CULL_EPS (-13.815511f)        // ln(1e-6): cull gaussians with max alpha < 1e-6

// Single fused kernel. Block = one 8x8 pixel tile (x batch) = 512 threads = 8 waves.
// Phase 1: all threads cooperatively recompute per-gaussian params (cull extent +
//          alpha-polynomial + packed color) for this batch's 768 gaussians into LDS.
//          Redundant across blocks but replaces a separate launch + HBM round-trip.
// Phase 2: wave w box-culls chunk w (96 gaussians) against the tile; order-preserving
//          ballot compaction of survivor INDICES into this wave's LDS region.
// Phase 3: wave w composites its survivors via wave-uniform broadcast ds_reads.
// Phase 4: partials (r,g,b,T) folded back-to-front across the 8 waves via LDS;
//          waves 0..2 each write one color plane.
__global__ __launch_bounds__(512)
void gr_fused(const float* __restrict__ means,
              const float* __restrict__ scales,
              const float* __restrict__ rots,
              const float* __restrict__ colors,
              const float* __restrict__ opac,
              float* __restrict__ out) {
    __shared__ float4 ldsCull[NG];          // (mx,my,ex,ey)            12 KB
    __shared__ float4 ldsPay[NG * 2];       // (A,B,C,D),(E,F,rg,cb)    24 KB
    __shared__ int    ldsIdx[NWAVE][CHUNK]; //                           3 KB
    __shared__ float4 partl[NWAVE][64];     //                           8 KB

    int tid  = threadIdx.x;
    int wave = tid >> 6;
    int lane = tid & 63;
    int tile = blockIdx.x;                  // [0, 400)
    int b    = blockIdx.y;

    // ---- Phase 1: param recompute into LDS (768 gaussians / 512 threads) ----
    for (int g = tid; g < NG; g += 512) {
        int i = b * NG + g;
        float theta = rots[i];
        float c = cosf(theta), s = sinf(theta);
        float sx = scales[2*i], sy = scales[2*i+1];
        float sx2 = sx*sx, sy2 = sy*sy;
        float a  = c*c*sx2 + s*s*sy2;
        float bb = c*s*(sx2 - sy2);
        float d  = s*s*sx2 + c*c*sy2;
        float mx = means[2*i], my = means[2*i+1];
        float cxx = a + SZ2_*mx*mx + EPS2D_;
        float cxy = bb + SZ2_*mx*my;
        float cyy = d + SZ2_*my*my + EPS2D_;
        float det = cxx*cyy - cxy*cxy;
        float inv = 1.0f / det;
        float ca  =  cyy * inv;
        float cb2 = -cxy * inv;
        float cc  =  cxx * inv;
        float op  = opac[i];

        // influence extent: alpha >= 1e-6 => |dx|<=k*sqrt(cxx), |dy|<=k*sqrt(cyy)
        float k2 = fmaxf(2.0f * (logf(op) - LN_CULL_EPS), 0.0f);
        float kk = sqrtf(k2);
        ldsCull[g] = make_float4(mx, my, kk * sqrtf(cxx), kk * sqrtf(cyy));

        float A = KEXP * ca;
        float Bq = KEXP * 2.0f * cb2;
        float C = KEXP * cc;
        float D = KEXP * (-2.0f * ca * mx - 2.0f * cb2 * my);
        float E = KEXP * (-2.0f * cc * my - 2.0f * cb2 * mx);
        float F = KEXP * (ca*mx*mx + 2.0f*cb2*mx*my + cc*my*my) + log2f(op);
        __half2 h2 = __floats2half2_rn(colors[3*i], colors[3*i+1]);
        float rg; memcpy(&rg, &h2, 4);
        ldsPay[2*g]   = make_float4(A, Bq, C, D);
        ldsPay[2*g+1] = make_float4(E, F, rg, colors[3*i+2]);
    }
    __syncthreads();

    int tx = tile % TPD, ty = tile / TPD;
    int pxi = tx * TILE + (lane & 7);
    int pyi = ty * TILE + (lane >> 3);
    float px = (float)pxi + 0.5f;
    float py = (float)pyi + 0.5f;
    float cxm = (float)(tx * TILE) + 0.5f * TILE;   // tile center
    float cym = (float)(ty * TILE) + 0.5f * TILE;
    const float RH = 0.5f * TILE;                   // tile half-extent
    float x2 = px*px, xy = px*py, y2 = py*py;

    // ---- Phase 2: cull chunk `wave` + index compaction (64 + 32) ----
    int base = wave * CHUNK;
    int cnt = 0;
    {
        float4 cu = ldsCull[base + lane];
        bool keep = (fabsf(cu.x - cxm) <= cu.z + RH) &&
                    (fabsf(cu.y - cym) <= cu.w + RH);
        unsigned long long m = __ballot(keep);
        unsigned pre = __builtin_amdgcn_mbcnt_hi((unsigned)(m >> 32),
                        __builtin_amdgcn_mbcnt_lo((unsigned)m, 0u));
        if (keep) ldsIdx[wave][pre] = base + lane;
        cnt = (int)__popcll(m);
    }
    {
        bool valid = lane < (CHUNK - 64);
        float4 cu = ldsCull[base + 64 + (valid ? lane : 0)];
        bool keep = valid &&
                    (fabsf(cu.x - cxm) <= cu.z + RH) &&
                    (fabsf(cu.y - cym) <= cu.w + RH);
        unsigned long long m = __ballot(keep);
        unsigned pre = __builtin_amdgcn_mbcnt_hi((unsigned)(m >> 32),
                        __builtin_amdgcn_mbcnt_lo((unsigned)m, 0u));
        if (keep) ldsIdx[wave][cnt + (int)pre] = base + 64 + lane;
        cnt += (int)__popcll(m);
    }

    // ---- Phase 3: composite survivors (wave-uniform broadcast reads) ----
    float R = 0.f, G = 0.f, B = 0.f, T = 1.f;
    for (int i = 0; i < cnt; ++i) {
        int idx = ldsIdx[wave][i];
        float4 av = ldsPay[2*idx];
        float4 ev = ldsPay[2*idx + 1];
        float q = fmaf(av.x, x2,
                  fmaf(av.y, xy,
                  fmaf(av.z, y2,
                  fmaf(av.w, px,
                  fmaf(ev.x, py, ev.y)))));
        float al = fminf(__builtin_exp2f(q), ALPHA_MAX_);
        float w  = T * al;
        __half2 h2; memcpy(&h2, &ev.z, 4);
        float2 rg = __half22float2(h2);
        R  = fmaf(w, rg.x, R);
        G  = fmaf(w, rg.y, G);
        B  = fmaf(w, ev.w, B);
        T -= w;
        if (((i & 7) == 7) && __all(T < 1.0e-4f)) break;
    }

    // ---- Phase 4: fold the 8 wave-partials back-to-front; write planes ----
    partl[wave][lane] = make_float4(R, G, B, T);
    __syncthreads();

    float4 o = partl[NWAVE-1][lane];
    float r = o.x, g = o.y, bb = o.z;
    #pragma unroll
    for (int i = NWAVE-2; i >= 0; --i) {
        float4 oi = partl[i][lane];
        r  = fmaf(oi.w, r,  oi.x);
        g  = fmaf(oi.w, g,  oi.y);
        bb = fmaf(oi.w, bb, oi.z);
    }
    if (wave < 3) {
        float v = (wave == 0) ? r : (wave == 1) ? g : bb;
        v = fminf(fmaxf(v, 0.f), 1.f);
        out[(b * 3 + wave) * NPIX + pyi * W_ + pxi] = v;
    }
}

extern "C" void kernel_launch(void* const* d_in, const int* in_sizes, int n_in,
                              void* d_out, int out_size, void* d_ws, size_t ws_size,
                              hipStream_t stream) {
    const float* means  = (const float*)d_in[0];
    const float* scales = (const float*)d_in[1];
    const float* rots   = (const float*)d_in[2];
    const float* colors = (const float*)d_in[3];
    const float* opac   = (const float*)d_in[4];
    float* out = (float*)d_out;

    dim3 grid(NTILE, BATCH);                      // (400, 2) x 512 threads
    gr_fused<<<grid, 512, 0, stream>>>(means, scales, rots, colors, opac, out);
}

// Round 7
// 72.142 us; speedup vs baseline: 1.0309x; 1.0309x over previous
//
#include <hip/hip_runtime.h>
#include <hip/hip_fp16.h>
#include <string.h>

// Problem constants (match setup_inputs: B=2, N=768, H=W=160)
#define BATCH   2
#define NG      768
#define H_      160
#define W_      160
#define NPIX    (H_ * W_)          // 25600
#define NWAVE   8
#define CHUNK   (NG / NWAVE)       // 96
#define TILE    8
#define TPD     (W_ / TILE)        // 20 tiles per dim
#define NTILE   (TPD * TPD)        // 400
#define EPS2D_  0.3f
#define SZ2_    1.0e-6f            // 0.001^2
#define ALPHA_MAX_ 0.999f
#define KEXP    (-0.7213475204444817f)   // -0.5 * log2(e)
#define LN_CULL_EPS (-13.815511f)        // ln(1e-6): cull gaussians with max alpha < 1e-6

// cull[i]    = (mx, my, ex, ey)            : mean + axis-aligned influence extent
// pay[2i]    = (A, B, C, D)                : alpha = min(exp2(A x^2+B xy+C y^2+D x+E y+F), .999)
// pay[2i+1]  = (E, F, half2(cr,cg), cb)

__global__ __launch_bounds__(256)
void gr_precompute(const float* __restrict__ means,
                   const float* __restrict__ scales,
                   const float* __restrict__ rots,
                   const float* __restrict__ colors,
                   const float* __restrict__ opac,
                   float4* __restrict__ cull, float4* __restrict__ pay, int total) {
    int i = blockIdx.x * blockDim.x + threadIdx.x;
    if (i >= total) return;
    float theta = rots[i];
    float c, s;
    __sincosf(theta, &s, &c);                 // HW v_sin/v_cos path
    float sx = scales[2*i], sy = scales[2*i+1];
    float sx2 = sx*sx, sy2 = sy*sy;
    float a  = c*c*sx2 + s*s*sy2;
    float bb = c*s*(sx2 - sy2);
    float d  = s*s*sx2 + c*c*sy2;
    float mx = means[2*i], my = means[2*i+1];
    float cxx = a + SZ2_*mx*mx + EPS2D_;
    float cxy = bb + SZ2_*mx*my;
    float cyy = d + SZ2_*my*my + EPS2D_;
    float det = cxx*cyy - cxy*cxy;
    float inv = 1.0f / det;
    float ca  =  cyy * inv;
    float cb2 = -cxy * inv;
    float cc  =  cxx * inv;
    float op  = opac[i];

    // influence extent: alpha >= 1e-6  =>  |dx| <= k*sqrt(cxx), |dy| <= k*sqrt(cyy)
    float lg2op = __log2f(op);
    float k2 = fmaxf(2.0f * (0.6931472f * lg2op - LN_CULL_EPS), 0.0f);
    float kk = sqrtf(k2);
    cull[i] = make_float4(mx, my, kk * sqrtf(cxx), kk * sqrtf(cyy));

    float A = KEXP * ca;
    float B = KEXP * 2.0f * cb2;
    float C = KEXP * cc;
    float D = KEXP * (-2.0f * ca * mx - 2.0f * cb2 * my);
    float E = KEXP * (-2.0f * cc * my - 2.0f * cb2 * mx);
    float F = KEXP * (ca*mx*mx + 2.0f*cb2*mx*my + cc*my*my) + lg2op;
    __half2 h2 = __floats2half2_rn(colors[3*i], colors[3*i+1]);
    float rg; memcpy(&rg, &h2, 4);
    pay[2*i]   = make_float4(A, B, C, D);
    pay[2*i+1] = make_float4(E, F, rg, colors[3*i+2]);
}

// Fused render+combine. Block = one 8x8 pixel tile x 8 waves (512 threads).
// Wave w composites chunk w (96 gaussians): box-cull vs tile -> order-preserving
// ballot compaction of survivor payloads into this wave's LDS region ->
// composite via wave-uniform broadcast ds_read. One barrier, then all waves
// fold the 8 partials back-to-front; waves 0..2 write one color plane each.
// LDS = 24 KB stage + 8 KB partials = 32 KB -> 4 blocks/CU = 32 waves/CU (100%).
__global__ __launch_bounds__(512)
void gr_render(const float4* __restrict__ cull, const float4* __restrict__ pay,
               float* __restrict__ out) {
    __shared__ float4 stage[NWAVE][CHUNK * 2];   // survivor payloads, per wave
    __shared__ float4 partl[NWAVE][64];
    int tid  = threadIdx.x;
    int wave = tid >> 6;
    int lane = tid & 63;
    int tile = blockIdx.x;                   // [0, 400)
    int b    = blockIdx.y;
    int tx = tile % TPD, ty = tile / TPD;
    int pxi = tx * TILE + (lane & 7);
    int pyi = ty * TILE + (lane >> 3);
    float px = (float)pxi + 0.5f;
    float py = (float)pyi + 0.5f;
    float cxm = (float)(tx * TILE) + 0.5f * TILE;   // tile center
    float cym = (float)(ty * TILE) + 0.5f * TILE;
    const float RH = 0.5f * TILE;                   // tile half-extent (4)
    float x2 = px*px, xy = px*py, y2 = py*py;

    int base = b * NG + wave * CHUNK;
    int cnt = 0;

    {   // cull batch 0: gaussians [0, 64)
        float4 cu = cull[base + lane];
        bool keep = (fabsf(cu.x - cxm) <= cu.z + RH) &&
                    (fabsf(cu.y - cym) <= cu.w + RH);
        unsigned long long m = __ballot(keep);
        unsigned pre = __builtin_amdgcn_mbcnt_hi((unsigned)(m >> 32),
                        __builtin_amdgcn_mbcnt_lo((unsigned)m, 0u));
        if (keep) {
            int gi = base + lane;
            stage[wave][2*pre]     = pay[2*gi];
            stage[wave][2*pre + 1] = pay[2*gi + 1];
        }
        cnt = (int)__popcll(m);
    }
    {   // cull batch 1: gaussians [64, 96) — lanes 32..63 idle
        bool valid = lane < (CHUNK - 64);
        int gi = base + 64 + (valid ? lane : 0);   // clamped, in-bounds
        float4 cu = cull[gi];
        bool keep = valid &&
                    (fabsf(cu.x - cxm) <= cu.z + RH) &&
                    (fabsf(cu.y - cym) <= cu.w + RH);
        unsigned long long m = __ballot(keep);
        unsigned pre = __builtin_amdgcn_mbcnt_hi((unsigned)(m >> 32),
                        __builtin_amdgcn_mbcnt_lo((unsigned)m, 0u));
        if (keep) {
            int slot = cnt + (int)pre;
            stage[wave][2*slot]     = pay[2*gi];
            stage[wave][2*slot + 1] = pay[2*gi + 1];
        }
        cnt += (int)__popcll(m);
    }

    // composite survivors (broadcast ds_read, wave-uniform address)
    float R = 0.f, G = 0.f, B = 0.f, T = 1.f;
    for (int i = 0; i < cnt; ++i) {
        float4 av = stage[wave][2*i];
        float4 ev = stage[wave][2*i + 1];
        float q = fmaf(av.x, x2,
                  fmaf(av.y, xy,
                  fmaf(av.z, y2,
                  fmaf(av.w, px,
                  fmaf(ev.x, py, ev.y)))));
        float al = fminf(__builtin_exp2f(q), ALPHA_MAX_);
        float w  = T * al;
        __half2 h2; memcpy(&h2, &ev.z, 4);
        float2 rg = __half22float2(h2);
        R  = fmaf(w, rg.x, R);
        G  = fmaf(w, rg.y, G);
        B  = fmaf(w, ev.w, B);
        T -= w;
        if (((i & 7) == 7) && __all(T < 1.0e-4f)) break;
    }

    partl[wave][lane] = make_float4(R, G, B, T);
    __syncthreads();

    // fold the 8 wave-partials back-to-front; waves 0..2 write plane = wave
    float4 o = partl[NWAVE-1][lane];
    float r = o.x, g = o.y, bb = o.z;
    #pragma unroll
    for (int i = NWAVE-2; i >= 0; --i) {
        float4 oi = partl[i][lane];
        r  = fmaf(oi.w, r,  oi.x);
        g  = fmaf(oi.w, g,  oi.y);
        bb = fmaf(oi.w, bb, oi.z);
    }
    if (wave < 3) {
        float v = (wave == 0) ? r : (wave == 1) ? g : bb;
        v = fminf(fmaxf(v, 0.f), 1.f);
        out[(b * 3 + wave) * NPIX + pyi * W_ + pxi] = v;
    }
}

extern "C" void kernel_launch(void* const* d_in, const int* in_sizes, int n_in,
                              void* d_out, int out_size, void* d_ws, size_t ws_size,
                              hipStream_t stream) {
    const float* means  = (const float*)d_in[0];
    const float* scales = (const float*)d_in[1];
    const float* rots   = (const float*)d_in[2];
    const float* colors = (const float*)d_in[3];
    const float* opac   = (const float*)d_in[4];
    float* out = (float*)d_out;

    int total = BATCH * NG;                       // 1536
    float4* cullA = (float4*)d_ws;                // 1536 * 16 B
    float4* pay   = cullA + total;                // 1536 * 32 B

    gr_precompute<<<(total + 255) / 256, 256, 0, stream>>>(
        means, scales, rots, colors, opac, cullA, pay, total);

    dim3 rgrid(NTILE, BATCH);                     // (400, 2) x 512 threads
    gr_render<<<rgrid, 512, 0, stream>>>(cullA, pay, out);
}